// Round 1
// baseline (597.302 us; speedup 1.0000x reference)
//
#include <hip/hip_runtime.h>
#include <math.h>

#define NN 100000
#define F0 128
#define F1 16
#define F2 10

static constexpr int SCAN_T = 256;
static constexpr int SCAN_I = 8;
static constexpr int SCAN_C = SCAN_T * SCAN_I;          // 2048 items per block
static constexpr int NB = (NN + 1 + SCAN_C - 1) / SCAN_C;  // 49 scan blocks

__device__ inline void fma4(float4& a, float s, const float4& w) {
  a.x = fmaf(s, w.x, a.x);
  a.y = fmaf(s, w.y, a.y);
  a.z = fmaf(s, w.z, a.z);
  a.w = fmaf(s, w.w, a.w);
}

// ---- degree (includes self-loop: init to 1) ----
__global__ void k_init_deg(int* __restrict__ deg) {
  int i = blockIdx.x * blockDim.x + threadIdx.x;
  if (i < NN) deg[i] = 1;
}

__global__ void k_count(const int* __restrict__ dst, int E, int* __restrict__ deg) {
  int i = blockIdx.x * blockDim.x + threadIdx.x;
  int stride = gridDim.x * blockDim.x;
  for (int e = i; e < E; e += stride) atomicAdd(&deg[dst[e]], 1);
}

__global__ void k_dinv(const int* __restrict__ deg, float* __restrict__ dinv) {
  int i = blockIdx.x * blockDim.x + threadIdx.x;
  if (i < NN) dinv[i] = rsqrtf((float)deg[i]);  // deg >= 1 always (self-loop)
}

// ---- exclusive scan of cnt[i] = deg[i]-1 over N+1 entries -> row_start ----
__global__ void k_scan1(const int* __restrict__ deg, int* __restrict__ bsum) {
  __shared__ int lds[SCAN_T];
  int t = threadIdx.x, b = blockIdx.x;
  int base = b * SCAN_C + t * SCAN_I;
  int s = 0;
#pragma unroll
  for (int k = 0; k < SCAN_I; k++) {
    int i = base + k;
    if (i < NN) s += deg[i] - 1;
  }
  lds[t] = s;
  __syncthreads();
  for (int off = SCAN_T / 2; off > 0; off >>= 1) {
    if (t < off) lds[t] += lds[t + off];
    __syncthreads();
  }
  if (t == 0) bsum[b] = lds[0];
}

__global__ void k_scan2(const int* __restrict__ bsum, int* __restrict__ boff) {
  __shared__ int lds[64];
  int t = threadIdx.x;
  int v = (t < NB) ? bsum[t] : 0;
  lds[t] = v;
  __syncthreads();
  for (int off = 1; off < 64; off <<= 1) {
    int add = (t >= off) ? lds[t - off] : 0;
    __syncthreads();
    lds[t] += add;
    __syncthreads();
  }
  if (t < NB) boff[t] = lds[t] - v;  // exclusive
}

__global__ void k_scan3(const int* __restrict__ deg, const int* __restrict__ boff,
                        int* __restrict__ row_start, int* __restrict__ cursor) {
  __shared__ int lds[SCAN_T];
  int t = threadIdx.x, b = blockIdx.x;
  int base = b * SCAN_C + t * SCAN_I;
  int loc[SCAN_I];
  int s = 0;
#pragma unroll
  for (int k = 0; k < SCAN_I; k++) {
    int i = base + k;
    int c = (i < NN) ? deg[i] - 1 : 0;
    loc[k] = s;
    s += c;
  }
  lds[t] = s;
  __syncthreads();
  for (int off = 1; off < SCAN_T; off <<= 1) {
    int add = (t >= off) ? lds[t - off] : 0;
    __syncthreads();
    lds[t] += add;
    __syncthreads();
  }
  int off0 = boff[b] + (lds[t] - s);  // exclusive thread offset
#pragma unroll
  for (int k = 0; k < SCAN_I; k++) {
    int i = base + k;
    if (i <= NN) {
      int v = off0 + loc[k];
      row_start[i] = v;
      if (i < NN) cursor[i] = v;
    }
  }
}

__global__ void k_scatter(const int* __restrict__ src, const int* __restrict__ dst, int E,
                          int* __restrict__ cursor, int* __restrict__ col) {
  int i = blockIdx.x * blockDim.x + threadIdx.x;
  int stride = gridDim.x * blockDim.x;
  for (int e = i; e < E; e += stride) {
    int d = dst[e];
    int pos = atomicAdd(&cursor[d], 1);
    col[pos] = src[e];
  }
}

// ---- h1 = x @ W1  (100000x128 @ 128x16), 4 rows/thread, W1 in LDS ----
__global__ __launch_bounds__(256) void k_lin1(const float* __restrict__ x,
                                              const float* __restrict__ W1,
                                              float* __restrict__ h1) {
  __shared__ float4 wl[F0 * 4];  // [k][jq], 8 KB
  int t = threadIdx.x;
  for (int i = t; i < F0 * 4; i += 256) wl[i] = ((const float4*)W1)[i];
  __syncthreads();
  int row0 = (blockIdx.x * 256 + t) * 4;
  if (row0 >= NN) return;  // N % 4 == 0 -> all 4 rows valid when row0 < N
  float4 acc[4][4];
#pragma unroll
  for (int r = 0; r < 4; r++)
#pragma unroll
    for (int j = 0; j < 4; j++) acc[r][j] = make_float4(0.f, 0.f, 0.f, 0.f);
  const float4* xr0 = (const float4*)(x + (size_t)(row0 + 0) * F0);
  const float4* xr1 = (const float4*)(x + (size_t)(row0 + 1) * F0);
  const float4* xr2 = (const float4*)(x + (size_t)(row0 + 2) * F0);
  const float4* xr3 = (const float4*)(x + (size_t)(row0 + 3) * F0);
  for (int k4 = 0; k4 < F0 / 4; k4++) {
    float4 xv[4];
    xv[0] = xr0[k4]; xv[1] = xr1[k4]; xv[2] = xr2[k4]; xv[3] = xr3[k4];
#pragma unroll
    for (int kk = 0; kk < 4; kk++) {
      float4 w0 = wl[(k4 * 4 + kk) * 4 + 0];
      float4 w1 = wl[(k4 * 4 + kk) * 4 + 1];
      float4 w2 = wl[(k4 * 4 + kk) * 4 + 2];
      float4 w3 = wl[(k4 * 4 + kk) * 4 + 3];
#pragma unroll
      for (int r = 0; r < 4; r++) {
        float xs = kk == 0 ? xv[r].x : kk == 1 ? xv[r].y : kk == 2 ? xv[r].z : xv[r].w;
        fma4(acc[r][0], xs, w0);
        fma4(acc[r][1], xs, w1);
        fma4(acc[r][2], xs, w2);
        fma4(acc[r][3], xs, w3);
      }
    }
  }
#pragma unroll
  for (int r = 0; r < 4; r++) {
    float4* hr = (float4*)(h1 + (size_t)(row0 + r) * F1);
#pragma unroll
    for (int j = 0; j < 4; j++) hr[j] = acc[r][j];
  }
}

// ---- layer-1 aggregation + bias + ReLU; 4 threads per dst (one quad each) ----
__global__ void k_agg1(const float* __restrict__ h1, const int* __restrict__ row_start,
                       const int* __restrict__ col, const float* __restrict__ dinv,
                       const float* __restrict__ b1, float* __restrict__ h1r) {
  int t = blockIdx.x * blockDim.x + threadIdx.x;
  int d = t >> 2, q = t & 3;
  if (d >= NN) return;
  float dd = dinv[d];
  float sw = dd * dd;  // self-loop weight
  float4 acc = ((const float4*)(h1 + (size_t)d * F1))[q];
  acc.x *= sw; acc.y *= sw; acc.z *= sw; acc.w *= sw;
  int e1 = row_start[d + 1];
  for (int e = row_start[d]; e < e1; e++) {
    int s = col[e];
    float w = dinv[s] * dd;
    float4 hv = ((const float4*)(h1 + (size_t)s * F1))[q];
    fma4(acc, w, hv);
  }
  float4 bb = ((const float4*)b1)[q];
  acc.x = fmaxf(acc.x + bb.x, 0.f);
  acc.y = fmaxf(acc.y + bb.y, 0.f);
  acc.z = fmaxf(acc.z + bb.z, 0.f);
  acc.w = fmaxf(acc.w + bb.w, 0.f);
  ((float4*)(h1r + (size_t)d * F1))[q] = acc;
}

// ---- h2 = h1r @ W2, padded to stride 16 (cols 10..15 zero) ----
__global__ void k_lin2(const float* __restrict__ h1r, const float* __restrict__ W2,
                       float* __restrict__ h2) {
  __shared__ float4 wl[F1 * 4];  // [k][jq], cols >= 10 zeroed
  int t = threadIdx.x;
  if (t < F1 * 4) {
    int k = t >> 2, jq = t & 3;
    float tmp[4];
#pragma unroll
    for (int c = 0; c < 4; c++) {
      int j = jq * 4 + c;
      tmp[c] = (j < F2) ? W2[k * F2 + j] : 0.f;
    }
    wl[t] = make_float4(tmp[0], tmp[1], tmp[2], tmp[3]);
  }
  __syncthreads();
  int row = blockIdx.x * blockDim.x + t;
  if (row >= NN) return;
  const float4* hr = (const float4*)(h1r + (size_t)row * F1);
  float4 acc[4];
#pragma unroll
  for (int j = 0; j < 4; j++) acc[j] = make_float4(0.f, 0.f, 0.f, 0.f);
#pragma unroll
  for (int k4 = 0; k4 < 4; k4++) {
    float4 hv = hr[k4];
#pragma unroll
    for (int kk = 0; kk < 4; kk++) {
      int k = k4 * 4 + kk;
      float hs = kk == 0 ? hv.x : kk == 1 ? hv.y : kk == 2 ? hv.z : hv.w;
#pragma unroll
      for (int jq = 0; jq < 4; jq++) fma4(acc[jq], hs, wl[k * 4 + jq]);
    }
  }
  float4* o = (float4*)(h2 + (size_t)row * 16);
#pragma unroll
  for (int j = 0; j < 4; j++) o[j] = acc[j];
}

// ---- layer-2 aggregation + bias + log_softmax; one thread per dst ----
__global__ void k_agg2(const float* __restrict__ h2, const int* __restrict__ row_start,
                       const int* __restrict__ col, const float* __restrict__ dinv,
                       const float* __restrict__ b2, float* __restrict__ out) {
  int d = blockIdx.x * blockDim.x + threadIdx.x;
  if (d >= NN) return;
  float dd = dinv[d];
  float sw = dd * dd;
  const float4* hr = (const float4*)(h2 + (size_t)d * 16);
  float4 a0 = hr[0], a1 = hr[1], a2 = hr[2];
  a0.x *= sw; a0.y *= sw; a0.z *= sw; a0.w *= sw;
  a1.x *= sw; a1.y *= sw; a1.z *= sw; a1.w *= sw;
  a2.x *= sw; a2.y *= sw; a2.z *= sw; a2.w *= sw;
  int e1 = row_start[d + 1];
  for (int e = row_start[d]; e < e1; e++) {
    int s = col[e];
    float w = dinv[s] * dd;
    const float4* hs = (const float4*)(h2 + (size_t)s * 16);
    fma4(a0, w, hs[0]);
    fma4(a1, w, hs[1]);
    fma4(a2, w, hs[2]);
  }
  float v[12];
  v[0] = a0.x; v[1] = a0.y; v[2] = a0.z; v[3] = a0.w;
  v[4] = a1.x; v[5] = a1.y; v[6] = a1.z; v[7] = a1.w;
  v[8] = a2.x; v[9] = a2.y; v[10] = a2.z; v[11] = a2.w;
#pragma unroll
  for (int j = 0; j < F2; j++) v[j] += b2[j];
  float m = v[0];
#pragma unroll
  for (int j = 1; j < F2; j++) m = fmaxf(m, v[j]);
  float sum = 0.f;
#pragma unroll
  for (int j = 0; j < F2; j++) sum += expf(v[j] - m);
  float lse = m + logf(sum);
  float* o = out + (size_t)d * F2;
#pragma unroll
  for (int j = 0; j < F2; j++) o[j] = v[j] - lse;
}

extern "C" void kernel_launch(void* const* d_in, const int* in_sizes, int n_in,
                              void* d_out, int out_size, void* d_ws, size_t ws_size,
                              hipStream_t stream) {
  const float* x  = (const float*)d_in[0];
  const int*   ei = (const int*)d_in[1];
  const float* W1 = (const float*)d_in[2];
  const float* b1 = (const float*)d_in[3];
  const float* W2 = (const float*)d_in[4];
  const float* b2 = (const float*)d_in[5];
  float* out = (float*)d_out;
  int E = in_sizes[1] / 2;
  const int* src = ei;       // edge_index[0]
  const int* dst = ei + E;   // edge_index[1]

  char* p = (char*)d_ws;
  auto alloc = [&](size_t bytes) {
    char* r = p;
    p += (bytes + 255) & ~(size_t)255;
    return r;
  };
  int*   deg       = (int*)alloc((size_t)NN * 4);
  float* dinv      = (float*)alloc((size_t)NN * 4);
  int*   row_start = (int*)alloc((size_t)(NN + 1) * 4);
  int*   cursor    = (int*)alloc((size_t)NN * 4);
  int*   bsum      = (int*)alloc((size_t)NB * 4);
  int*   boff      = (int*)alloc((size_t)NB * 4);
  int*   col       = (int*)alloc((size_t)E * 4);
  float* h1        = (float*)alloc((size_t)NN * F1 * 4);
  float* h1r       = (float*)alloc((size_t)NN * F1 * 4);
  float* h2        = (float*)alloc((size_t)NN * 16 * 4);

  int nblkN = (NN + 255) / 256;
  hipLaunchKernelGGL(k_init_deg, dim3(nblkN), dim3(256), 0, stream, deg);
  hipLaunchKernelGGL(k_count, dim3(2048), dim3(256), 0, stream, dst, E, deg);
  hipLaunchKernelGGL(k_dinv, dim3(nblkN), dim3(256), 0, stream, deg, dinv);
  hipLaunchKernelGGL(k_scan1, dim3(NB), dim3(SCAN_T), 0, stream, deg, bsum);
  hipLaunchKernelGGL(k_scan2, dim3(1), dim3(64), 0, stream, bsum, boff);
  hipLaunchKernelGGL(k_scan3, dim3(NB), dim3(SCAN_T), 0, stream, deg, boff, row_start, cursor);
  hipLaunchKernelGGL(k_scatter, dim3(2048), dim3(256), 0, stream, src, dst, E, cursor, col);
  hipLaunchKernelGGL(k_lin1, dim3((NN / 4 + 255) / 256), dim3(256), 0, stream, x, W1, h1);
  hipLaunchKernelGGL(k_agg1, dim3((NN * 4 + 255) / 256), dim3(256), 0, stream,
                     h1, row_start, col, dinv, b1, h1r);
  hipLaunchKernelGGL(k_lin2, dim3(nblkN), dim3(256), 0, stream, h1r, W2, h2);
  hipLaunchKernelGGL(k_agg2, dim3(nblkN), dim3(256), 0, stream, h2, row_start, col, dinv, b2, out);
}

// Round 2
// 294.750 us; speedup vs baseline: 2.0265x; 2.0265x over previous
//
#include <hip/hip_runtime.h>
#include <math.h>

#define NN 100000
#define F0 128
#define F1 16
#define F2 10
#define NBUCK 391   // ceil(NN / 256); bucket b covers dsts [b*256, b*256+255]
#define TILE 16384  // edges per binplace block
#define CAP 16384   // LDS staging capacity in k_bucket (mean bucket ~8.2K, >6 sigma headroom)

__device__ inline void fma4(float4& a, float s, const float4& w) {
  a.x = fmaf(s, w.x, a.x);
  a.y = fmaf(s, w.y, a.y);
  a.z = fmaf(s, w.z, a.z);
  a.w = fmaf(s, w.w, a.w);
}

// ---- zero coarse bucket counters ----
__global__ void k_zero(int* __restrict__ bucket_cnt) {
  int i = blockIdx.x * blockDim.x + threadIdx.x;
  if (i < NBUCK) bucket_cnt[i] = 0;
}

// ---- coarse histogram: LDS per block, one global atomic per bucket per block ----
__global__ __launch_bounds__(256) void k_bincount(const int* __restrict__ dst, int E,
                                                  int* __restrict__ bucket_cnt) {
  __shared__ int hist[NBUCK];
  int t = threadIdx.x;
  for (int i = t; i < NBUCK; i += 256) hist[i] = 0;
  __syncthreads();
  int per = (E + gridDim.x - 1) / gridDim.x;
  int e0 = blockIdx.x * per, e1 = min(E, e0 + per);
  for (int e = e0 + t; e < e1; e += 256) atomicAdd(&hist[dst[e] >> 8], 1);
  __syncthreads();
  for (int i = t; i < NBUCK; i += 256)
    if (hist[i]) atomicAdd(&bucket_cnt[i], hist[i]);
}

// ---- exclusive scan of bucket counts -> bucket_base, init bucket_cur ----
__global__ void k_binscan(const int* __restrict__ bucket_cnt, int* __restrict__ bucket_base,
                          int* __restrict__ bucket_cur) {
  __shared__ int lds[512];
  int t = threadIdx.x;
  int v = (t < NBUCK) ? bucket_cnt[t] : 0;
  lds[t] = v;
  __syncthreads();
  for (int o = 1; o < 512; o <<= 1) {
    int add = (t >= o) ? lds[t - o] : 0;
    __syncthreads();
    lds[t] += add;
    __syncthreads();
  }
  if (t < NBUCK) {
    int excl = lds[t] - v;
    bucket_base[t] = excl;
    bucket_cur[t] = excl;
    if (t == NBUCK - 1) bucket_base[NBUCK] = lds[t];  // == E
  }
}

// ---- coarse partition: grouped writes of packed payload (src<<8 | dst&255) ----
__global__ __launch_bounds__(256) void k_binplace(const int* __restrict__ src,
                                                  const int* __restrict__ dst, int E,
                                                  int* __restrict__ bucket_cur,
                                                  int* __restrict__ packed) {
  __shared__ int hbase[NBUCK];
  __shared__ int hcur[NBUCK];
  int t = threadIdx.x;
  int e0 = blockIdx.x * TILE, e1 = min(E, e0 + TILE);
  for (int i = t; i < NBUCK; i += 256) { hbase[i] = 0; hcur[i] = 0; }
  __syncthreads();
  for (int e = e0 + t; e < e1; e += 256) atomicAdd(&hbase[dst[e] >> 8], 1);
  __syncthreads();
  for (int i = t; i < NBUCK; i += 256) {
    int c = hbase[i];
    hbase[i] = (c > 0) ? atomicAdd(&bucket_cur[i], c) : 0;
  }
  __syncthreads();
  for (int e = e0 + t; e < e1; e += 256) {
    int d = dst[e];
    int bk = d >> 8;
    int pos = atomicAdd(&hcur[bk], 1);
    packed[hbase[bk] + pos] = (src[e] << 8) | (d & 255);
  }
}

// ---- fine pass: per-bucket LDS histogram/scan/scatter; emits row_start, dinv, col ----
__global__ __launch_bounds__(256) void k_bucket(const int* __restrict__ packed,
                                                const int* __restrict__ bucket_base,
                                                int* __restrict__ row_start,
                                                float* __restrict__ dinv,
                                                int* __restrict__ col, int E) {
  __shared__ int stage[CAP];
  __shared__ int hist[256];
  __shared__ int off[256];
  __shared__ int cur[256];
  int b = blockIdx.x, t = threadIdx.x;
  int base = bucket_base[b];
  int cnt = bucket_base[b + 1] - base;
  hist[t] = 0;
  bool staged = (cnt <= CAP);
  if (staged)
    for (int i = t; i < cnt; i += 256) stage[i] = packed[base + i];
  __syncthreads();
  if (staged) {
    for (int i = t; i < cnt; i += 256) atomicAdd(&hist[stage[i] & 255], 1);
  } else {
    for (int i = t; i < cnt; i += 256) atomicAdd(&hist[packed[base + i] & 255], 1);
  }
  __syncthreads();
  int v = hist[t];
  off[t] = v;
  __syncthreads();
  for (int o = 1; o < 256; o <<= 1) {
    int add = (t >= o) ? off[t - o] : 0;
    __syncthreads();
    off[t] += add;
    __syncthreads();
  }
  int excl = off[t] - v;
  cur[t] = excl;
  int d = b * 256 + t;
  if (d < NN) {
    row_start[d] = base + excl;
    dinv[d] = rsqrtf((float)(v + 1));  // +1 self-loop
  }
  if (b == 0 && t == 0) row_start[NN] = E;
  __syncthreads();
  if (staged) {
    for (int i = t; i < cnt; i += 256) {
      int p = stage[i];
      int pos = atomicAdd(&cur[p & 255], 1);
      col[base + pos] = p >> 8;
    }
  } else {
    for (int i = t; i < cnt; i += 256) {
      int p = packed[base + i];
      int pos = atomicAdd(&cur[p & 255], 1);
      col[base + pos] = p >> 8;
    }
  }
}

// ---- h1 = x @ W1  (100000x128 @ 128x16), 4 rows/thread, W1 in LDS ----
__global__ __launch_bounds__(256) void k_lin1(const float* __restrict__ x,
                                              const float* __restrict__ W1,
                                              float* __restrict__ h1) {
  __shared__ float4 wl[F0 * 4];  // [k][jq], 8 KB
  int t = threadIdx.x;
  for (int i = t; i < F0 * 4; i += 256) wl[i] = ((const float4*)W1)[i];
  __syncthreads();
  int row0 = (blockIdx.x * 256 + t) * 4;
  if (row0 >= NN) return;  // N % 4 == 0
  float4 acc[4][4];
#pragma unroll
  for (int r = 0; r < 4; r++)
#pragma unroll
    for (int j = 0; j < 4; j++) acc[r][j] = make_float4(0.f, 0.f, 0.f, 0.f);
  const float4* xr0 = (const float4*)(x + (size_t)(row0 + 0) * F0);
  const float4* xr1 = (const float4*)(x + (size_t)(row0 + 1) * F0);
  const float4* xr2 = (const float4*)(x + (size_t)(row0 + 2) * F0);
  const float4* xr3 = (const float4*)(x + (size_t)(row0 + 3) * F0);
  for (int k4 = 0; k4 < F0 / 4; k4++) {
    float4 xv[4];
    xv[0] = xr0[k4]; xv[1] = xr1[k4]; xv[2] = xr2[k4]; xv[3] = xr3[k4];
#pragma unroll
    for (int kk = 0; kk < 4; kk++) {
      float4 w0 = wl[(k4 * 4 + kk) * 4 + 0];
      float4 w1 = wl[(k4 * 4 + kk) * 4 + 1];
      float4 w2 = wl[(k4 * 4 + kk) * 4 + 2];
      float4 w3 = wl[(k4 * 4 + kk) * 4 + 3];
#pragma unroll
      for (int r = 0; r < 4; r++) {
        float xs = kk == 0 ? xv[r].x : kk == 1 ? xv[r].y : kk == 2 ? xv[r].z : xv[r].w;
        fma4(acc[r][0], xs, w0);
        fma4(acc[r][1], xs, w1);
        fma4(acc[r][2], xs, w2);
        fma4(acc[r][3], xs, w3);
      }
    }
  }
#pragma unroll
  for (int r = 0; r < 4; r++) {
    float4* hr = (float4*)(h1 + (size_t)(row0 + r) * F1);
#pragma unroll
    for (int j = 0; j < 4; j++) hr[j] = acc[r][j];
  }
}

// ---- layer-1 aggregation + bias + ReLU; 4 threads per dst ----
__global__ void k_agg1(const float* __restrict__ h1, const int* __restrict__ row_start,
                       const int* __restrict__ col, const float* __restrict__ dinv,
                       const float* __restrict__ b1, float* __restrict__ h1r) {
  int t = blockIdx.x * blockDim.x + threadIdx.x;
  int d = t >> 2, q = t & 3;
  if (d >= NN) return;
  float dd = dinv[d];
  float sw = dd * dd;
  float4 acc = ((const float4*)(h1 + (size_t)d * F1))[q];
  acc.x *= sw; acc.y *= sw; acc.z *= sw; acc.w *= sw;
  int e1 = row_start[d + 1];
  for (int e = row_start[d]; e < e1; e++) {
    int s = col[e];
    float w = dinv[s] * dd;
    float4 hv = ((const float4*)(h1 + (size_t)s * F1))[q];
    fma4(acc, w, hv);
  }
  float4 bb = ((const float4*)b1)[q];
  acc.x = fmaxf(acc.x + bb.x, 0.f);
  acc.y = fmaxf(acc.y + bb.y, 0.f);
  acc.z = fmaxf(acc.z + bb.z, 0.f);
  acc.w = fmaxf(acc.w + bb.w, 0.f);
  ((float4*)(h1r + (size_t)d * F1))[q] = acc;
}

// ---- h2 = h1r @ W2, padded to stride 16 (cols 10..15 zero) ----
__global__ void k_lin2(const float* __restrict__ h1r, const float* __restrict__ W2,
                       float* __restrict__ h2) {
  __shared__ float4 wl[F1 * 4];
  int t = threadIdx.x;
  if (t < F1 * 4) {
    int k = t >> 2, jq = t & 3;
    float tmp[4];
#pragma unroll
    for (int c = 0; c < 4; c++) {
      int j = jq * 4 + c;
      tmp[c] = (j < F2) ? W2[k * F2 + j] : 0.f;
    }
    wl[t] = make_float4(tmp[0], tmp[1], tmp[2], tmp[3]);
  }
  __syncthreads();
  int row = blockIdx.x * blockDim.x + t;
  if (row >= NN) return;
  const float4* hr = (const float4*)(h1r + (size_t)row * F1);
  float4 acc[4];
#pragma unroll
  for (int j = 0; j < 4; j++) acc[j] = make_float4(0.f, 0.f, 0.f, 0.f);
#pragma unroll
  for (int k4 = 0; k4 < 4; k4++) {
    float4 hv = hr[k4];
#pragma unroll
    for (int kk = 0; kk < 4; kk++) {
      int k = k4 * 4 + kk;
      float hs = kk == 0 ? hv.x : kk == 1 ? hv.y : kk == 2 ? hv.z : hv.w;
#pragma unroll
      for (int jq = 0; jq < 4; jq++) fma4(acc[jq], hs, wl[k * 4 + jq]);
    }
  }
  float4* o = (float4*)(h2 + (size_t)row * 16);
#pragma unroll
  for (int j = 0; j < 4; j++) o[j] = acc[j];
}

// ---- layer-2 aggregation + bias + log_softmax; one thread per dst ----
__global__ void k_agg2(const float* __restrict__ h2, const int* __restrict__ row_start,
                       const int* __restrict__ col, const float* __restrict__ dinv,
                       const float* __restrict__ b2, float* __restrict__ out) {
  int d = blockIdx.x * blockDim.x + threadIdx.x;
  if (d >= NN) return;
  float dd = dinv[d];
  float sw = dd * dd;
  const float4* hr = (const float4*)(h2 + (size_t)d * 16);
  float4 a0 = hr[0], a1 = hr[1], a2 = hr[2];
  a0.x *= sw; a0.y *= sw; a0.z *= sw; a0.w *= sw;
  a1.x *= sw; a1.y *= sw; a1.z *= sw; a1.w *= sw;
  a2.x *= sw; a2.y *= sw; a2.z *= sw; a2.w *= sw;
  int e1 = row_start[d + 1];
  for (int e = row_start[d]; e < e1; e++) {
    int s = col[e];
    float w = dinv[s] * dd;
    const float4* hs = (const float4*)(h2 + (size_t)s * 16);
    fma4(a0, w, hs[0]);
    fma4(a1, w, hs[1]);
    fma4(a2, w, hs[2]);
  }
  float v[12];
  v[0] = a0.x; v[1] = a0.y; v[2] = a0.z; v[3] = a0.w;
  v[4] = a1.x; v[5] = a1.y; v[6] = a1.z; v[7] = a1.w;
  v[8] = a2.x; v[9] = a2.y; v[10] = a2.z; v[11] = a2.w;
#pragma unroll
  for (int j = 0; j < F2; j++) v[j] += b2[j];
  float m = v[0];
#pragma unroll
  for (int j = 1; j < F2; j++) m = fmaxf(m, v[j]);
  float sum = 0.f;
#pragma unroll
  for (int j = 0; j < F2; j++) sum += expf(v[j] - m);
  float lse = m + logf(sum);
  float* o = out + (size_t)d * F2;
#pragma unroll
  for (int j = 0; j < F2; j++) o[j] = v[j] - lse;
}

extern "C" void kernel_launch(void* const* d_in, const int* in_sizes, int n_in,
                              void* d_out, int out_size, void* d_ws, size_t ws_size,
                              hipStream_t stream) {
  const float* x  = (const float*)d_in[0];
  const int*   ei = (const int*)d_in[1];
  const float* W1 = (const float*)d_in[2];
  const float* b1 = (const float*)d_in[3];
  const float* W2 = (const float*)d_in[4];
  const float* b2 = (const float*)d_in[5];
  float* out = (float*)d_out;
  int E = in_sizes[1] / 2;
  const int* src = ei;
  const int* dst = ei + E;

  char* p = (char*)d_ws;
  auto alloc = [&](size_t bytes) {
    char* r = p;
    p += (bytes + 255) & ~(size_t)255;
    return r;
  };
  float* dinv        = (float*)alloc((size_t)NN * 4);
  int*   row_start   = (int*)alloc((size_t)(NN + 1) * 4);
  int*   bucket_cnt  = (int*)alloc((size_t)NBUCK * 4);
  int*   bucket_base = (int*)alloc((size_t)(NBUCK + 1) * 4);
  int*   bucket_cur  = (int*)alloc((size_t)NBUCK * 4);
  int*   col         = (int*)alloc((size_t)E * 4);
  // regionA: packed (E ints) is dead after k_bucket; h1+h1r (2*NN*F1 floats) overlay it.
  size_t regA = (size_t)E * 4;
  size_t hsz = (size_t)NN * F1 * 4 * 2;
  char*  A = (char*)alloc(regA > hsz ? regA : hsz);
  int*   packed = (int*)A;
  float* h1  = (float*)A;
  float* h1r = (float*)(A + (size_t)NN * F1 * 4);
  float* h2  = (float*)alloc((size_t)NN * 16 * 4);

  int nblkN = (NN + 255) / 256;
  int nblk_place = (E + TILE - 1) / TILE;
  hipLaunchKernelGGL(k_zero, dim3(2), dim3(256), 0, stream, bucket_cnt);
  hipLaunchKernelGGL(k_bincount, dim3(256), dim3(256), 0, stream, dst, E, bucket_cnt);
  hipLaunchKernelGGL(k_binscan, dim3(1), dim3(512), 0, stream, bucket_cnt, bucket_base, bucket_cur);
  hipLaunchKernelGGL(k_binplace, dim3(nblk_place), dim3(256), 0, stream, src, dst, E, bucket_cur, packed);
  hipLaunchKernelGGL(k_bucket, dim3(NBUCK), dim3(256), 0, stream, packed, bucket_base, row_start, dinv, col, E);
  hipLaunchKernelGGL(k_lin1, dim3((NN / 4 + 255) / 256), dim3(256), 0, stream, x, W1, h1);
  hipLaunchKernelGGL(k_agg1, dim3((NN * 4 + 255) / 256), dim3(256), 0, stream,
                     h1, row_start, col, dinv, b1, h1r);
  hipLaunchKernelGGL(k_lin2, dim3(nblkN), dim3(256), 0, stream, h1r, W2, h2);
  hipLaunchKernelGGL(k_agg2, dim3(nblkN), dim3(256), 0, stream, h2, row_start, col, dinv, b2, out);
}